// Round 3
// baseline (2486.509 us; speedup 1.0000x reference)
//
#include <hip/hip_runtime.h>
#include <math.h>

#define TAU 0.25f   // |pivot|^2 threshold for the fast pivot path

// ---------------------------------------------------------------------------
// Fused kernel. Grid = 5120 blocks of 256 threads:
//   blockIdx % 5 == 4  -> conv slab block   (1024 of them)
//   blockIdx % 5 <  4  -> logdet key block  (4096 of them; 4 waves = 4 batches)
// Fusing lets conv's LDS-pipe-heavy blocks overlap logdet's VALU-heavy blocks.
// ---------------------------------------------------------------------------
__global__ __launch_bounds__(256, 3) void fused_kernel(
    const float* __restrict__ x, const float* __restrict__ K,
    const float* __restrict__ bias, float* __restrict__ out,
    float* __restrict__ logdet) {
  __shared__ float smem[1792];           // conv: tile 18x67 + w 576; logdet: 4x128
  int bid = blockIdx.x;
  int q = bid / 5;
  int m5 = bid - q * 5;
  int t = threadIdx.x;

  if (m5 == 4) {
    // ================= conv: circular 3x3, per-sample kernels =================
    // q in 0..1023: 4 slabs x 64 co x 4 b. 16 output rows per block.
    int slab = q & 3, co = (q >> 2) & 63, b = q >> 8;
    float* tile = smem;                  // [18][67]; word = 67*r + 1 + col, col -1..64
    float* w = smem + 1206;              // 576 weights (identity fused)

    for (int i = t; i < 576; i += 256) {
      float v = K[(size_t)(b * 64 + co) * 576 + i];
      if (i == co * 9 + 4) v += 1.0f;    // identity: ci==co, center tap
      w[i] = v;
    }

    int y0 = slab << 4;
    int yr = t >> 4;                     // 0..15: output row in slab
    int c0 = (t & 15) << 2;              // 0..60: 4 output cols per thread
    float bval = bias[b * 64 + co];
    float a0 = bval, a1 = bval, a2 = bval, a3 = bval;
    const float* xb = x + (size_t)(b * 64) * 4096;

    for (int ci = 0; ci < 64; ++ci) {
      __syncthreads();                   // WAR on tile (and w on first iter)
      const float* xc = xb + (size_t)ci * 4096;
      // bulk stage: 18 rows x 64 cols as float4 global loads, scalar LDS writes
#pragma unroll
      for (int it = 0; it < 2; ++it) {
        int i = t + it * 256;
        if (i < 288) {
          int rr = i >> 4, c4 = (i & 15) << 2;
          float4 v4 = *(const float4*)(xc + (((y0 - 1 + rr) & 63) << 6) + c4);
          int base = rr * 67 + 1 + c4;
          tile[base] = v4.x; tile[base + 1] = v4.y;
          tile[base + 2] = v4.z; tile[base + 3] = v4.w;
        }
      }
      if (t < 36) {                      // halo cols: -1 (copy 63), 64 (copy 0)
        int rr = t >> 1;
        int gy = (((y0 - 1 + rr) & 63) << 6);
        if (t & 1) tile[rr * 67 + 65] = xc[gy];        // col 64
        else       tile[rr * 67]      = xc[gy + 63];   // col -1
      }
      __syncthreads();

      float w0 = w[ci * 9 + 0], w1 = w[ci * 9 + 1], w2 = w[ci * 9 + 2];
      float w3 = w[ci * 9 + 3], w4 = w[ci * 9 + 4], w5 = w[ci * 9 + 5];
      float w6 = w[ci * 9 + 6], w7 = w[ci * 9 + 7], w8 = w[ci * 9 + 8];

      // tile word = 67*(yr+dy) + 1 + (c0+dx-1) = 67*row + c0 + dx
      int rm = yr * 67, rc = rm + 67, rp = rm + 134;
      float i0[6], i1[6], i2[6];
#pragma unroll
      for (int dx = 0; dx < 6; ++dx) {
        int o = c0 + dx;
        i0[dx] = tile[rm + o]; i1[dx] = tile[rc + o]; i2[dx] = tile[rp + o];
      }
      a0 = fmaf(w0, i0[0], a0); a0 = fmaf(w1, i0[1], a0); a0 = fmaf(w2, i0[2], a0);
      a0 = fmaf(w3, i1[0], a0); a0 = fmaf(w4, i1[1], a0); a0 = fmaf(w5, i1[2], a0);
      a0 = fmaf(w6, i2[0], a0); a0 = fmaf(w7, i2[1], a0); a0 = fmaf(w8, i2[2], a0);
      a1 = fmaf(w0, i0[1], a1); a1 = fmaf(w1, i0[2], a1); a1 = fmaf(w2, i0[3], a1);
      a1 = fmaf(w3, i1[1], a1); a1 = fmaf(w4, i1[2], a1); a1 = fmaf(w5, i1[3], a1);
      a1 = fmaf(w6, i2[1], a1); a1 = fmaf(w7, i2[2], a1); a1 = fmaf(w8, i2[3], a1);
      a2 = fmaf(w0, i0[2], a2); a2 = fmaf(w1, i0[3], a2); a2 = fmaf(w2, i0[4], a2);
      a2 = fmaf(w3, i1[2], a2); a2 = fmaf(w4, i1[3], a2); a2 = fmaf(w5, i1[4], a2);
      a2 = fmaf(w6, i2[2], a2); a2 = fmaf(w7, i2[3], a2); a2 = fmaf(w8, i2[4], a2);
      a3 = fmaf(w0, i0[3], a3); a3 = fmaf(w1, i0[4], a3); a3 = fmaf(w2, i0[5], a3);
      a3 = fmaf(w3, i1[3], a3); a3 = fmaf(w4, i1[4], a3); a3 = fmaf(w5, i1[5], a3);
      a3 = fmaf(w6, i2[3], a3); a3 = fmaf(w7, i2[4], a3); a3 = fmaf(w8, i2[5], a3);
    }

    float* op = out + (size_t)(b * 64 + co) * 4096 + ((y0 + yr) << 6) + c0;
    *(float4*)op = make_float4(a0, a1, a2, a3);
    return;
  }

  // ================= logdet: per-frequency 64x64 complex LU =================
  int key = q * 4 + m5;                  // 0..4095
  int u = key >> 6, v = key & 63;
  int key2 = (((64 - u) & 63) << 6) | ((64 - v) & 63);
  if (key2 < key) return;                // conjugate partner handles it
  float weight = (key2 == key) ? 1.0f : 2.0f;

  int wv = t >> 6;                       // wave id == batch b
  int r = t & 63;                        // lane == matrix row
  float* Lr = smem + wv * 128;
  float* Li = Lr + 64;

  // twiddles e^{-2*pi*i*(u*kh+v*kw)/64} via complex power products
  float Ar[3], Ai[3], Br[3], Bi[3];
  {
    const float k2pi = -6.283185307179586f / 64.0f;
    float su, cu, sv, cv;
    __sincosf(k2pi * (float)u, &su, &cu);
    __sincosf(k2pi * (float)v, &sv, &cv);
    Ar[0] = 1.0f; Ai[0] = 0.0f; Ar[1] = cu; Ai[1] = su;
    Ar[2] = cu * cu - su * su; Ai[2] = 2.0f * cu * su;
    Br[0] = 1.0f; Bi[0] = 0.0f; Br[1] = cv; Bi[1] = sv;
    Br[2] = cv * cv - sv * sv; Bi[2] = 2.0f * cv * sv;
  }
  float wr[9], wi[9];
#pragma unroll
  for (int kh = 0; kh < 3; ++kh)
#pragma unroll
    for (int kw = 0; kw < 3; ++kw) {
      wr[kh * 3 + kw] = Ar[kh] * Br[kw] - Ai[kh] * Bi[kw];
      wi[kh * 3 + kw] = Ar[kh] * Bi[kw] + Ai[kh] * Br[kw];
    }

  // Build row r of Khat (aligned float4 loads; row = 576 floats)
  float ar[65], ai[65];
  const float4* Kp4 = (const float4*)(K + (size_t)(wv * 64 + r) * 576);
#pragma unroll
  for (int g = 0; g < 16; ++g) {
    float f[36];
#pragma unroll
    for (int qq = 0; qq < 9; ++qq) {
      float4 vv = Kp4[g * 9 + qq];
      f[qq * 4 + 0] = vv.x; f[qq * 4 + 1] = vv.y; f[qq * 4 + 2] = vv.z; f[qq * 4 + 3] = vv.w;
    }
#pragma unroll
    for (int cc = 0; cc < 4; ++cc) {
      int c = g * 4 + cc;
      float re = 0.0f, im = 0.0f;
#pragma unroll
      for (int t9 = 0; t9 < 9; ++t9) {
        float kv = f[cc * 9 + t9];
        re = fmaf(kv, wr[t9], re);
        im = fmaf(kv, wi[t9], im);
      }
      if (c == r) { re += wr[4]; im += wi[4]; }  // identity: center-tap delta
      ar[c] = re; ai[c] = im;
    }
  }
  ar[64] = 0.0f; ai[64] = 0.0f;          // pad read by chunk 3

  bool active = true;
  float logsum = 0.0f;

  for (int k = 0; k < 63; ++k) {
    float mag = fmaf(ar[0], ar[0], ai[0] * ai[0]);
    bool cand = active && (mag >= TAU);
    unsigned long long candm = __ballot(cand);
    int p;
    if (candm != 0ULL) {
      p = __ffsll(candm) - 1;            // fast path: first big-enough pivot
    } else {                             // rare: all remaining pivots tiny -> max
      float mm = active ? mag : -1.0f;
#pragma unroll
      for (int off = 32; off > 0; off >>= 1) mm = fmaxf(mm, __shfl_xor(mm, off));
      unsigned long long mx = __ballot(active && (mag == mm));
      p = __ffsll(mx) - 1;
    }
    float pr = __shfl(ar[0], p);
    float pi = __shfl(ai[0], p);
    int rem = 63 - k;                    // remaining columns at indices 1..rem

    if (r == p) {                        // retire pivot lane: log + broadcast row
      logsum += 0.5f * __logf(mag);
      active = false;
#pragma unroll
      for (int ch = 0; ch < 4; ++ch) {
        if (ch * 16 < rem) {
#pragma unroll
          for (int j = 0; j < 4; ++j) {
            int c = ch * 16 + j * 4 + 1;
            ((float4*)Lr)[ch * 4 + j] = make_float4(ar[c], ar[c + 1], ar[c + 2], ar[c + 3]);
            ((float4*)Li)[ch * 4 + j] = make_float4(ai[c], ai[c + 1], ai[c + 2], ai[c + 3]);
          }
        }
      }
    }
    // same-wave DS ops retire in order; no barrier needed. Keep compiler fence.
    __builtin_amdgcn_wave_barrier();

    float m2 = fmaf(pr, pr, pi * pi);
    float inv = 1.0f / m2;
    float fre = (ar[0] * pr + ai[0] * pi) * inv;
    float fim = (ai[0] * pr - ar[0] * pi) * inv;
    fre = active ? fre : 0.0f;           // pivot + retired lanes: shift-only
    fim = active ? fim : 0.0f;

#pragma unroll
    for (int ch = 0; ch < 4; ++ch) {
      if (ch * 16 < rem) {
#pragma unroll
        for (int j = 0; j < 4; ++j) {
          float4 l4r = ((float4*)Lr)[ch * 4 + j];
          float4 l4i = ((float4*)Li)[ch * 4 + j];
          float lrA[4] = {l4r.x, l4r.y, l4r.z, l4r.w};
          float liA[4] = {l4i.x, l4i.y, l4i.z, l4i.w};
          int c0 = ch * 16 + j * 4 + 1;
#pragma unroll
          for (int e = 0; e < 4; ++e) {
            int c = c0 + e;
            float nr = fmaf(fim, liA[e], fmaf(-fre, lrA[e], ar[c]));
            float ni = fmaf(-fim, lrA[e], fmaf(-fre, liA[e], ai[c]));
            ar[c - 1] = nr;              // compaction shift: pivot col -> index 0
            ai[c - 1] = ni;
          }
        }
      }
    }
    __builtin_amdgcn_wave_barrier();
  }
  if (active) logsum += 0.5f * __logf(fmaf(ar[0], ar[0], ai[0] * ai[0]));

#pragma unroll
  for (int off = 32; off > 0; off >>= 1) logsum += __shfl_xor(logsum, off);
  if (r == 0) atomicAdd(&logdet[wv], weight * logsum);
}

// ---------------------------------------------------------------------------
extern "C" void kernel_launch(void* const* d_in, const int* in_sizes, int n_in,
                              void* d_out, int out_size, void* d_ws, size_t ws_size,
                              hipStream_t stream) {
  const float* conv_in = (const float*)d_in[0];   // [4,64,64,64]
  const float* K       = (const float*)d_in[1];   // [4,64,64,3,3]
  const float* bias    = (const float*)d_in[2];   // [4,64,1,1]
  float* out = (float*)d_out;                     // conv_out (1048576) ++ logdet (4)
  float* logdet = out + 1048576;

  hipMemsetAsync(logdet, 0, 4 * sizeof(float), stream);
  fused_kernel<<<dim3(5120), dim3(256), 0, stream>>>(conv_in, K, bias, out, logdet);
}

// Round 4
// 506.759 us; speedup vs baseline: 4.9067x; 4.9067x over previous
//
#include <hip/hip_runtime.h>
#include <math.h>

#define CCH 64
#define NSP 64
#define TAU 0.25f   // |pivot|^2 threshold for the fast pivot path

// ---------------------------------------------------------------------------
// Kernel 1: circular 3x3 conv, per-sample kernels, + bias, + identity kernel.
// (round-1 version, known-good ~70us; not the bottleneck this round)
// ---------------------------------------------------------------------------
__global__ __launch_bounds__(256) void conv_kernel(
    const float* __restrict__ x, const float* __restrict__ K,
    const float* __restrict__ bias, float* __restrict__ out) {
  int bid = blockIdx.x;            // 0..255
  int b = bid >> 6, co = bid & 63;
  __shared__ float w[CCH * 9];
  __shared__ float tile[64 * 65];
  int t = threadIdx.x;

  for (int i = t; i < CCH * 9; i += 256) {
    float v = K[(size_t)((b * 64 + co) * 64) * 9 + i];
    if (i == co * 9 + 4) v += 1.0f;   // identity: ci==co, kh=kw=1
    w[i] = v;
  }

  int ty = t >> 2;
  int tx = t & 3;
  int x0 = tx << 4;
  float bval = bias[b * 64 + co];
  float acc[16];
#pragma unroll
  for (int i = 0; i < 16; ++i) acc[i] = bval;

  const float* xb = x + (size_t)(b * 64) * 4096;
  for (int ci = 0; ci < 64; ++ci) {
    __syncthreads();
    const float* xc = xb + (size_t)ci * 4096;
#pragma unroll
    for (int j = 0; j < 16; ++j) {
      int i = t + 256 * j;
      tile[(i >> 6) * 65 + (i & 63)] = xc[i];
    }
    __syncthreads();

    float w0 = w[ci * 9 + 0], w1 = w[ci * 9 + 1], w2 = w[ci * 9 + 2];
    float w3 = w[ci * 9 + 3], w4 = w[ci * 9 + 4], w5 = w[ci * 9 + 5];
    float w6 = w[ci * 9 + 6], w7 = w[ci * 9 + 7], w8 = w[ci * 9 + 8];

    int ym = ((ty - 1) & 63) * 65;
    int yc = ty * 65;
    int yp = ((ty + 1) & 63) * 65;
    float in0[18], in1[18], in2[18];
#pragma unroll
    for (int ix = 0; ix < 18; ++ix) {
      int xx = (x0 + ix - 1) & 63;
      in0[ix] = tile[ym + xx];
      in1[ix] = tile[yc + xx];
      in2[ix] = tile[yp + xx];
    }
#pragma unroll
    for (int px = 0; px < 16; ++px) {
      float a = acc[px];
      a = fmaf(w0, in0[px], a); a = fmaf(w1, in0[px + 1], a); a = fmaf(w2, in0[px + 2], a);
      a = fmaf(w3, in1[px], a); a = fmaf(w4, in1[px + 1], a); a = fmaf(w5, in1[px + 2], a);
      a = fmaf(w6, in2[px], a); a = fmaf(w7, in2[px + 1], a); a = fmaf(w8, in2[px + 2], a);
      acc[px] = a;
    }
  }

  float* op = out + (size_t)(b * 64 + co) * 4096 + ty * 64 + x0;
#pragma unroll
  for (int i = 0; i < 16; i += 4) {
    *(float4*)(op + i) = make_float4(acc[i], acc[i + 1], acc[i + 2], acc[i + 3]);
  }
}

// ---------------------------------------------------------------------------
// Kernel 2: per-frequency 64x64 complex LU -> sum log|pivot|.
// One wave per canonical (b,u,v); lane r owns row r, column-compacted so the
// pivot column is always register index 0. Pivot row is broadcast with
// v_readlane (uniform lane index) -- NO LDS, NO barriers in the k-loop.
// Lockstep guarantees lane p's ar[c]/ai[c] are still pre-update when read
// (this step only writes indices < c). Threshold pivoting: first lane with
// |piv|^2 >= TAU (one ballot); rare fallback to max-reduce. Each lane logs
// only its own pivot when retired; one wave-reduce at the end.
// ---------------------------------------------------------------------------
__device__ __forceinline__ float rlane(float x, int lane) {
  return __int_as_float(__builtin_amdgcn_readlane(__float_as_int(x), lane));
}

__global__ __launch_bounds__(64, 2) void logdet_kernel(
    const float* __restrict__ K, float* __restrict__ logdet) {
  int u = blockIdx.x >> 6, v = blockIdx.x & 63;
  int b = blockIdx.y;
  int key = blockIdx.x;
  int key2 = (((64 - u) & 63) << 6) | ((64 - v) & 63);
  if (key2 < key) return;                    // conjugate partner, weight 2 below
  float weight = (key2 == key) ? 1.0f : 2.0f;

  int r = threadIdx.x;                       // lane == matrix row

  // twiddles w[kh*3+kw] = e^{-2*pi*i*(u*kh+v*kw)/64} via complex power products
  float Ar[3], Ai[3], Br[3], Bi[3];
  {
    const float k2pi = -6.283185307179586f / 64.0f;
    float su, cu, sv, cv;
    __sincosf(k2pi * (float)u, &su, &cu);
    __sincosf(k2pi * (float)v, &sv, &cv);
    Ar[0] = 1.0f; Ai[0] = 0.0f; Ar[1] = cu; Ai[1] = su;
    Ar[2] = cu * cu - su * su; Ai[2] = 2.0f * cu * su;
    Br[0] = 1.0f; Bi[0] = 0.0f; Br[1] = cv; Bi[1] = sv;
    Br[2] = cv * cv - sv * sv; Bi[2] = 2.0f * cv * sv;
  }
  float wr[9], wi[9];
#pragma unroll
  for (int kh = 0; kh < 3; ++kh)
#pragma unroll
    for (int kw = 0; kw < 3; ++kw) {
      wr[kh * 3 + kw] = Ar[kh] * Br[kw] - Ai[kh] * Bi[kw];
      wi[kh * 3 + kw] = Ar[kh] * Bi[kw] + Ai[kh] * Br[kw];
    }

  // Build row r of Khat with aligned float4 loads (row = 576 floats)
  float ar[65], ai[65];
  const float4* Kp4 = (const float4*)(K + (size_t)(b * 64 + r) * 576);
#pragma unroll
  for (int g = 0; g < 16; ++g) {             // 16 groups x 4 columns
    float f[36];
#pragma unroll
    for (int qq = 0; qq < 9; ++qq) {
      float4 vv = Kp4[g * 9 + qq];
      f[qq * 4 + 0] = vv.x; f[qq * 4 + 1] = vv.y; f[qq * 4 + 2] = vv.z; f[qq * 4 + 3] = vv.w;
    }
#pragma unroll
    for (int cc = 0; cc < 4; ++cc) {
      int c = g * 4 + cc;
      float re = 0.0f, im = 0.0f;
#pragma unroll
      for (int t9 = 0; t9 < 9; ++t9) {
        float kv = f[cc * 9 + t9];
        re = fmaf(kv, wr[t9], re);
        im = fmaf(kv, wi[t9], im);
      }
      if (c == r) { re += wr[4]; im += wi[4]; }  // identity: center-tap delta
      ar[c] = re; ai[c] = im;
    }
  }
  ar[64] = 0.0f; ai[64] = 0.0f;              // pad slot read by chunk 3

  bool active = true;
  float logsum = 0.0f;

  for (int k = 0; k < 63; ++k) {
    float mag = fmaf(ar[0], ar[0], ai[0] * ai[0]);
    bool cand = active && (mag >= TAU);
    unsigned long long candm = __ballot(cand);
    int p;
    if (candm != 0ULL) {
      p = __ffsll(candm) - 1;                // fast path: first big-enough pivot
    } else {                                 // rare: all remaining pivots tiny
      float mm = active ? mag : -1.0f;
#pragma unroll
      for (int off = 32; off > 0; off >>= 1) mm = fmaxf(mm, __shfl_xor(mm, off));
      unsigned long long mx = __ballot(active && (mag == mm));
      p = __ffsll(mx) - 1;
    }

    if (r == p) {                            // retire pivot lane: log its pivot
      logsum += 0.5f * __logf(mag);
      active = false;
    }

    float pr = rlane(ar[0], p);
    float pi = rlane(ai[0], p);
    float inv = 1.0f / fmaf(pr, pr, pi * pi);
    float fre = (ar[0] * pr + ai[0] * pi) * inv;
    float fim = (ai[0] * pr - ar[0] * pi) * inv;
    fre = active ? fre : 0.0f;               // pivot + retired lanes: shift-only
    fim = active ? fim : 0.0f;

    int rem = 63 - k;                        // remaining columns at indices 1..rem
#pragma unroll
    for (int ch = 0; ch < 4; ++ch) {
      if (ch * 16 < rem) {                   // uniform scalar guard
#pragma unroll
        for (int j = 0; j < 16; ++j) {
          int c = ch * 16 + j + 1;
          float lr = rlane(ar[c], p);        // lane p's ar[c] not yet overwritten
          float li = rlane(ai[c], p);
          float nr = fmaf(fim, li, fmaf(-fre, lr, ar[c]));
          float ni = fmaf(-fim, lr, fmaf(-fre, li, ai[c]));
          ar[c - 1] = nr;                    // compaction shift
          ai[c - 1] = ni;
        }
      }
    }
  }
  if (active) logsum += 0.5f * __logf(fmaf(ar[0], ar[0], ai[0] * ai[0]));

#pragma unroll
  for (int off = 32; off > 0; off >>= 1) logsum += __shfl_xor(logsum, off);
  if (r == 0) atomicAdd(&logdet[b], weight * logsum);
}

// ---------------------------------------------------------------------------
extern "C" void kernel_launch(void* const* d_in, const int* in_sizes, int n_in,
                              void* d_out, int out_size, void* d_ws, size_t ws_size,
                              hipStream_t stream) {
  const float* conv_in = (const float*)d_in[0];   // [4,64,64,64]
  const float* K       = (const float*)d_in[1];   // [4,64,64,3,3]
  const float* bias    = (const float*)d_in[2];   // [4,64,1,1]
  float* out = (float*)d_out;                     // conv_out (1048576) ++ logdet (4)
  float* logdet = out + 1048576;

  hipMemsetAsync(logdet, 0, 4 * sizeof(float), stream);
  conv_kernel<<<dim3(256), dim3(256), 0, stream>>>(conv_in, K, bias, out);
  logdet_kernel<<<dim3(4096, 4), dim3(64), 0, stream>>>(K, logdet);
}